// Round 6
// baseline (303.229 us; speedup 1.0000x reference)
//
#include <hip/hip_runtime.h>
#include <math.h>

namespace {
constexpr int BB = 8;
constexpr int CH = 256;
constexpr int NN = 4096;
}

typedef float f32x4 __attribute__((ext_vector_type(4)));
typedef short bf16x8 __attribute__((ext_vector_type(8)));
typedef unsigned short us8 __attribute__((ext_vector_type(8)));
typedef unsigned int u32x4 __attribute__((ext_vector_type(4)));

#define MFMA16(a, b, c) __builtin_amdgcn_mfma_f32_16x16x32_bf16(a, b, c, 0, 0, 0)

__device__ __forceinline__ unsigned short f2bf(float x) {
    unsigned int u = __float_as_uint(x);
    u += 0x7fffu + ((u >> 16) & 1u);
    return (unsigned short)(u >> 16);
}
__device__ __forceinline__ float bf2f(unsigned short h) {
    return __uint_as_float(((unsigned int)h) << 16);
}
__device__ __forceinline__ void gload16(const void* g, void* l) {
    __builtin_amdgcn_global_load_lds(
        (const __attribute__((address_space(1))) unsigned int*)g,
        (__attribute__((address_space(3))) unsigned int*)l, 16, 0, 0);
}
__device__ __forceinline__ float vget(const float4& v, int p) {
    return (p == 0) ? v.x : (p == 1) ? v.y : (p == 2) ? v.z : v.w;
}

// ---------------------------------------------------------------------------
// Kernel 0: split W (wq|wk|wv, 320x256) into bf16 hi/lo.
// ---------------------------------------------------------------------------
__global__ __launch_bounds__(256) void wsplit_kernel(
    const float* __restrict__ wq, const float* __restrict__ wk,
    const float* __restrict__ wv,
    unsigned short* __restrict__ wh, unsigned short* __restrict__ wl)
{
    int idx = blockIdx.x * 256 + threadIdx.x;
    float v;
    if (idx < 8192)       v = wq[idx];
    else if (idx < 16384) v = wk[idx - 8192];
    else                  v = wv[idx - 16384];
    unsigned short hi = f2bf(v);
    wh[idx] = hi;
    wl[idx] = f2bf(v - bf2f(hi));
}

// ---------------------------------------------------------------------------
// Kernel 1: fused transpose + proj GEMM (MFMA, 3-term hi/lo split).
// Phase 1: paired-channel b32 LDS writes (conflict-free). Phase 2: MFMA
// K-loop with W prefetch. Epilogue -> qh/ql/kh/kl [b][n][32] (natural n),
// vt [b][c][n] with n PERMUTED within 32-blocks so attn PV A-frags line up
// with the in-register p B-frags (see attn kernel).
// ---------------------------------------------------------------------------
#define PJ_XH 0
#define PJ_XL 32768
#define PJ_VE 0        // epilogue aliases (after barrier)
#define PJ_QK 36864

__global__ __launch_bounds__(256, 2) void proj_kernel(
    const float* __restrict__ x,
    const unsigned short* __restrict__ wh, const unsigned short* __restrict__ wl,
    const float* __restrict__ bq, const float* __restrict__ bk,
    const float* __restrict__ bv,
    unsigned short* __restrict__ qh, unsigned short* __restrict__ ql,
    unsigned short* __restrict__ kh, unsigned short* __restrict__ kl,
    unsigned short* __restrict__ vt)
{
    __shared__ __align__(16) unsigned char smem[65536];
    const int t    = threadIdx.x;
    const int lane = t & 63;
    const int w    = t >> 6;
    const int l16  = lane & 15;
    const int quad = lane >> 4;
    const int b    = blockIdx.x >> 6;
    const int n0   = (blockIdx.x & 63) << 6;

    // ---- phase 1: thread owns channel pair (2cp,2cp+1) x 32 pixels
    const int cp   = t & 127;
    const int half = t >> 7;
    const float* xg = x + (size_t)b * 256 * NN + n0 + half * 32;
    float4 xa[8], xb[8];
    #pragma unroll
    for (int i = 0; i < 8; ++i) {
        xa[i] = *(const float4*)(xg + (size_t)(2 * cp) * NN + i * 4);
        xb[i] = *(const float4*)(xg + (size_t)(2 * cp + 1) * NN + i * 4);
    }
    #pragma unroll
    for (int i = 0; i < 8; ++i) {
        #pragma unroll
        for (int p = 0; p < 4; ++p) {
            const int n = half * 32 + i * 4 + p;
            float v0 = vget(xa[i], p), v1 = vget(xb[i], p);
            unsigned int h0 = f2bf(v0), h1 = f2bf(v1);
            unsigned int l0 = f2bf(v0 - bf2f((unsigned short)h0));
            unsigned int l1 = f2bf(v1 - bf2f((unsigned short)h1));
            const int chunk = (cp >> 2) ^ (n & 7);
            const int off = n * 512 + chunk * 16 + (cp & 3) * 4;
            *(unsigned int*)(smem + PJ_XH + off) = h0 | (h1 << 16);
            *(unsigned int*)(smem + PJ_XL + off) = l0 | (l1 << 16);
        }
    }

    // W(kc=0) prefetch before the barrier
    bf16x8 ah[2][5], al[2][5];
    #pragma unroll
    for (int i = 0; i < 5; ++i) {
        int och = (w * 5 + i) * 16 + l16;
        ah[0][i] = *(const bf16x8*)(wh + och * 256 + quad * 8);
        al[0][i] = *(const bf16x8*)(wl + och * 256 + quad * 8);
    }
    __syncthreads();

    // ---- phase 2: K-loop, wave w owns och-tiles w*5..w*5+4
    f32x4 acc[5][4] = {};
    #pragma unroll 2
    for (int kc = 0; kc < 8; ++kc) {
        if (kc < 7) {
            #pragma unroll
            for (int i = 0; i < 5; ++i) {
                int och = (w * 5 + i) * 16 + l16;
                ah[(kc + 1) & 1][i] = *(const bf16x8*)(wh + och * 256 + (kc + 1) * 32 + quad * 8);
                al[(kc + 1) & 1][i] = *(const bf16x8*)(wl + och * 256 + (kc + 1) * 32 + quad * 8);
            }
        }
        #pragma unroll
        for (int nt = 0; nt < 4; ++nt) {
            int roff = (nt * 16 + l16) * 512 + (((kc * 4 + quad) ^ (l16 & 7)) * 16);
            bf16x8 bh = *(const bf16x8*)(smem + PJ_XH + roff);
            bf16x8 bl = *(const bf16x8*)(smem + PJ_XL + roff);
            #pragma unroll
            for (int i = 0; i < 5; ++i) {
                acc[i][nt] = MFMA16(ah[kc & 1][i], bh, acc[i][nt]);
                acc[i][nt] = MFMA16(al[kc & 1][i], bh, acc[i][nt]);
                acc[i][nt] = MFMA16(ah[kc & 1][i], bl, acc[i][nt]);
            }
        }
    }
    __syncthreads();   // LDS reads done; alias epilogue regions

    // ---- epilogue
    #pragma unroll
    for (int i = 0; i < 5; ++i) {
        int tile = w * 5 + i;
        if (tile < 4) {  // q/k tiles (wave 0 only), natural n
            #pragma unroll
            for (int r = 0; r < 4; ++r) {
                int och = tile * 16 + quad * 4 + r;
                float bias = (och < 32) ? bq[och] : bk[och - 32];
                int arr = (och < 32) ? 0 : 2;
                int oq = och & 31;
                #pragma unroll
                for (int nt = 0; nt < 4; ++nt) {
                    float val = acc[i][nt][r] + bias;
                    unsigned short hi = f2bf(val);
                    unsigned short lo = f2bf(val - bf2f(hi));
                    *(unsigned short*)(smem + PJ_QK + arr * 4096 + (nt * 16 + l16) * 64 + oq * 2) = hi;
                    *(unsigned short*)(smem + PJ_QK + (arr + 1) * 4096 + (nt * 16 + l16) * 64 + oq * 2) = lo;
                }
            }
        } else {          // v tiles: key-permuted columns (within 32-blocks)
            #pragma unroll
            for (int r = 0; r < 4; ++r) {
                int voch = tile * 16 + quad * 4 + r - 64;
                float bias = bv[voch];
                #pragma unroll
                for (int nt = 0; nt < 4; ++nt) {
                    int col  = nt * 16 + l16;
                    int pcol = (col & 32) | ((col & 12) << 1) | (col & 3) | ((col >> 2) & 4);
                    *(unsigned short*)(smem + PJ_VE + voch * 136 + pcol * 2)
                        = f2bf(acc[i][nt][r] + bias);
                }
            }
        }
    }
    __syncthreads();

    {   // copy-out q/k: 4 arrays x 64 rows x 64B
        unsigned short* dsts[4] = { qh, ql, kh, kl };
        int arr = t >> 6, rn = t & 63;
        unsigned short* dst = dsts[arr] + ((size_t)b * NN + n0 + rn) * 32;
        #pragma unroll
        for (int i = 0; i < 4; ++i)
            *(us8*)(dst + i * 8) = *(const us8*)(smem + PJ_QK + arr * 4096 + rn * 64 + i * 16);
    }
    #pragma unroll
    for (int p = 0; p < 4; ++p) {   // copy-out v: 256 rows x 128B
        int voch = p * 64 + (t >> 2), piece = t & 3;
        unsigned short* dst = vt + ((size_t)b * CH + voch) * NN + n0 + piece * 16;
        *(us8*)(dst)     = *(const us8*)(smem + PJ_VE + voch * 136 + piece * 32);
        *(us8*)(dst + 8) = *(const us8*)(smem + PJ_VE + voch * 136 + piece * 32 + 16);
    }
}

// ---------------------------------------------------------------------------
// Kernel 2: MFMA flash attention, transposed-energy form, P never in LDS.
// Block = (b via &7, 64-query tile), 4 waves: qgrp=w&1 (32 q), cgrp=w>>1
// (128 ch). Per 64-key round: E2 = MFMA(K,Q) -> C row=key,col=query; exp+pack
// in regs forms the PV B-operand directly (vt pre-permuted to match). PV:
// acc^T[ch][q] += MFMA(V^T-frag from LDS, p-frag). One barrier per round;
// V tile DMA double-buffered; K frags global->VGPR ping-pong.
// ---------------------------------------------------------------------------
__global__ __launch_bounds__(256, 2) void attn_kernel(
    const unsigned short* __restrict__ qh, const unsigned short* __restrict__ ql,
    const unsigned short* __restrict__ kh, const unsigned short* __restrict__ kl,
    const unsigned short* __restrict__ vt, const float* __restrict__ gptr,
    float* __restrict__ out)
{
    __shared__ __align__(16) unsigned char smem[65536];  // V dbuf 2 x 32 KB
    const int t    = threadIdx.x;
    const int lane = t & 63;
    const int w    = t >> 6;
    const int l16  = lane & 15;
    const int quad = lane >> 4;
    const int b    = blockIdx.x & 7;
    const int n0   = (blockIdx.x >> 3) << 6;
    const int qgrp = w & 1;
    const int cgrp = w >> 1;

    // Q B-frags (2 query sub-tiles, hi/lo)
    bf16x8 qB[2][2];
    #pragma unroll
    for (int qt = 0; qt < 2; ++qt) {
        size_t row = (size_t)b * NN + n0 + qgrp * 32 + qt * 16 + l16;
        qB[qt][0] = *(const bf16x8*)(qh + row * 32 + quad * 8);
        qB[qt][1] = *(const bf16x8*)(ql + row * 32 + quad * 8);
    }

    const unsigned char* khb = (const unsigned char*)(kh + (size_t)b * NN * 32);
    const unsigned char* klb = (const unsigned char*)(kl + (size_t)b * NN * 32);
    // V DMA staging: thread -> (row = j*32 + (t>>3), chunk = t&7), XOR swizzle
    const int vr = t >> 3, vc = t & 7;
    const unsigned char* vsrc0 = (const unsigned char*)vt
        + (size_t)b * CH * NN * 2 + (size_t)vr * 8192 + (vc ^ (vr & 7)) * 16;

    // prologue: stage V(0), load K(0) frags
    #pragma unroll
    for (int j = 0; j < 8; ++j)
        gload16(vsrc0 + (size_t)j * 262144, smem + (j * 256 + t) * 16);
    bf16x8 khf[2][4], klf[2][4];
    #pragma unroll
    for (int kt = 0; kt < 4; ++kt) {
        khf[0][kt] = *(const bf16x8*)(khb + (kt * 16 + l16) * 64 + quad * 16);
        klf[0][kt] = *(const bf16x8*)(klb + (kt * 16 + l16) * 64 + quad * 16);
    }
    __syncthreads();

    f32x4 acc[8][2] = {};   // [ct][qt], C: row=ch, col=query
    float S[2] = {};
    unsigned int pk[2][4][2];

    #pragma unroll 2
    for (int r = 0; r < 64; ++r) {
        const int cur = r & 1, nxt = (r + 1) & 1;
        if (r < 63) {   // stage V(r+1) -> other buffer (drained at round-end barrier)
            #pragma unroll
            for (int j = 0; j < 8; ++j)
                gload16(vsrc0 + (size_t)j * 262144 + (size_t)(r + 1) * 128,
                        smem + nxt * 32768 + (j * 256 + t) * 16);
        }
        // E(r): 4 key-tiles x 2 query-tiles; p stays in registers
        #pragma unroll
        for (int kt = 0; kt < 4; ++kt) {
            #pragma unroll
            for (int qt = 0; qt < 2; ++qt) {
                f32x4 e = { 0.f, 0.f, 0.f, 0.f };
                e = MFMA16(khf[cur][kt], qB[qt][0], e);
                e = MFMA16(khf[cur][kt], qB[qt][1], e);
                e = MFMA16(klf[cur][kt], qB[qt][0], e);
                unsigned int pb[4];
                #pragma unroll
                for (int rr = 0; rr < 4; ++rr) {
                    float p = __expf(e[rr]);   // |e| << 88: no max shift needed
                    pb[rr] = f2bf(p);
                    S[qt] += bf2f((unsigned short)pb[rr]);
                }
                pk[qt][kt][0] = pb[0] | (pb[1] << 16);
                pk[qt][kt][1] = pb[2] | (pb[3] << 16);
            }
        }
        if (r < 63) {   // prefetch K(r+1) (consumed after next barrier)
            #pragma unroll
            for (int kt = 0; kt < 4; ++kt) {
                size_t off = (size_t)((r + 1) * 64 + kt * 16 + l16) * 64 + quad * 16;
                khf[nxt][kt] = *(const bf16x8*)(khb + off);
                klf[nxt][kt] = *(const bf16x8*)(klb + off);
            }
        }
        // PV(r): V^T A-frags from LDS (keys pre-permuted), p B-frags from regs
        const unsigned char* vb = smem + cur * 32768;
        #pragma unroll
        for (int s = 0; s < 2; ++s) {
            union { u32x4 u; bf16x8 v; } pf[2];
            #pragma unroll
            for (int qt = 0; qt < 2; ++qt) {
                pf[qt].u[0] = pk[qt][2 * s][0];
                pf[qt].u[1] = pk[qt][2 * s][1];
                pf[qt].u[2] = pk[qt][2 * s + 1][0];
                pf[qt].u[3] = pk[qt][2 * s + 1][1];
            }
            #pragma unroll
            for (int ct = 0; ct < 8; ++ct) {
                int row = cgrp * 128 + ct * 16 + l16;
                bf16x8 vf = *(const bf16x8*)
                    (vb + row * 128 + (((s * 4 + quad) ^ (l16 & 7)) * 16));
                acc[ct][0] = MFMA16(vf, pf[0].v, acc[ct][0]);
                acc[ct][1] = MFMA16(vf, pf[1].v, acc[ct][1]);
            }
        }
        __syncthreads();
    }

    // S: reduce across quads (keys) -> full sum per (query l16, qt)
    #pragma unroll
    for (int qt = 0; qt < 2; ++qt) {
        S[qt] += __shfl_xor(S[qt], 16);
        S[qt] += __shfl_xor(S[qt], 32);
    }
    const float g1 = 1.f + gptr[0];
    float is[2] = { g1 / S[0], g1 / S[1] };

    float* ob = out + (size_t)b * CH * NN;
    #pragma unroll
    for (int ct = 0; ct < 8; ++ct) {
        #pragma unroll
        for (int qt = 0; qt < 2; ++qt) {
            #pragma unroll
            for (int rr = 0; rr < 4; ++rr) {
                int ch = cgrp * 128 + ct * 16 + quad * 4 + rr;
                int n  = n0 + qgrp * 32 + qt * 16 + l16;
                float val = floorf(acc[ct][qt][rr] * is[qt] * 256.f) * 0.00390625f;
                ob[(size_t)ch * NN + n] = val;
            }
        }
    }
}

// ---------------------------------------------------------------------------
extern "C" void kernel_launch(void* const* d_in, const int* in_sizes, int n_in,
                              void* d_out, int out_size, void* d_ws, size_t ws_size,
                              hipStream_t stream) {
    const float* x  = (const float*)d_in[0];
    const float* wq = (const float*)d_in[1];
    const float* bq = (const float*)d_in[2];
    const float* wk = (const float*)d_in[3];
    const float* bk = (const float*)d_in[4];
    const float* wv = (const float*)d_in[5];
    const float* bv = (const float*)d_in[6];
    const float* gm = (const float*)d_in[7];
    float* out = (float*)d_out;

    unsigned short* ws = (unsigned short*)d_ws;
    const size_t WSZ = 320 * 256;
    const size_t QSZ = (size_t)BB * NN * 32;
    unsigned short* wh = ws;
    unsigned short* wl = wh + WSZ;
    unsigned short* qh = wl + WSZ;
    unsigned short* ql = qh + QSZ;
    unsigned short* kh = ql + QSZ;
    unsigned short* kl = kh + QSZ;
    unsigned short* vt = kl + QSZ;

    wsplit_kernel<<<320, 256, 0, stream>>>(wq, wk, wv, wh, wl);
    proj_kernel<<<512, 256, 0, stream>>>(x, wh, wl, bq, bk, bv,
                                         qh, ql, kh, kl, vt);
    attn_kernel<<<512, 256, 0, stream>>>(qh, ql, kh, kl, vt, gm, out);
}